// Round 10
// baseline (118.609 us; speedup 1.0000x reference)
//
#include <hip/hip_runtime.h>
#include <math.h>

#define T_LEN 2097152
#define K 8
#define D 4
#define CHUNK 8
#define TPB 64                         // single-wave workgroups
#define NBLK (T_LEN / (CHUNK * TPB))   // 4096 blocks
#define MS4 19                         // float4 stride per LDS matrix slot (76 floats, 16B-aligned)
#define NMID 32                        // stage-2 blocks
#define MPM (NBLK / NMID)              // 128 matrices per mid block

typedef float f2 __attribute__((ext_vector_type(2)));

__device__ __forceinline__ f2 fma2(f2 a, f2 b, f2 c) { return __builtin_elementwise_fma(a, b, c); }
__device__ __forceinline__ f2 max2(f2 a, f2 b) { return __builtin_elementwise_max(a, b); }
__device__ __forceinline__ f2 splat(float s) { f2 r; r.x = s; r.y = s; return r; }

// raw hardware exp2: skips the denorm-range fixup exp2f carries.
// Inputs are max-subtracted (<= 0); sub-denormal results are dead after renorm.
__device__ __forceinline__ float exp2_raw(float x) {
    float r;
    asm("v_exp_f32 %0, %1" : "=v"(r) : "v"(x));
    return r;
}

// ws layout (floats): [0..63] Tr; [64..71] a; [72..103] b; [104..135] c; [136..143] alpha0;
// [152] ticket counter (uint, zeroed by setup each iteration).
// [256..) bp (NBLK*64, transposed per-span), bs (NBLK, transposed), bp2 (NMID*64), bs2 (NMID)
//
// bp layout: matrix m -> span s = m>>7 (0..31), ml = m&127. float4 q of m lives at
// float4-index s*2048 + q*128 + ml. Mid block s reads float4s [s*2048 + k*256 + t]
// for k=0..7 -- lane-consecutive, fully coalesced. bs[s*128 + ml].

// LDS matrix slot li: float4 base = li*19 + ((li>>1)&3)  (bank-spreading swizzle,
// keeps all rows 16B-aligned; offset+63 <= 75 < 76 so slots never overlap)
__device__ __forceinline__ float4* matp4(float* lm, int li) {
    return reinterpret_cast<float4*>(lm) + li * MS4 + ((li >> 1) & 3);
}

__device__ __forceinline__ void renorm2(f2 M[K][4], float& shift) {
    f2 m2 = max2(max2(M[0][0], M[0][1]), max2(M[0][2], M[0][3]));
#pragma unroll
    for (int i = 1; i < K; ++i)
        m2 = max2(m2, max2(max2(M[i][0], M[i][1]), max2(M[i][2], M[i][3])));
    float mx = fmaxf(m2.x, m2.y);
    int ex = (__float_as_int(mx) >> 23) & 255;
    float scale = __int_as_float((254 - ex) << 23); // 2^(127-ex)
    shift += (float)(ex - 127);
    f2 sc = splat(scale);
#pragma unroll
    for (int i = 0; i < K; ++i)
#pragma unroll
        for (int jj = 0; jj < 4; ++jj) M[i][jj] = M[i][jj] * sc;
}

__device__ __forceinline__ void store_mat(float* lm, int li, const f2 M[K][4]) {
    float4* dst = matp4(lm, li);
#pragma unroll
    for (int i = 0; i < K; ++i) {
        float4 w0, w1;
        w0.x = M[i][0].x; w0.y = M[i][0].y; w0.z = M[i][1].x; w0.w = M[i][1].y;
        w1.x = M[i][2].x; w1.y = M[i][2].y; w1.z = M[i][3].x; w1.w = M[i][3].y;
        dst[i * 2] = w0;
        dst[i * 2 + 1] = w1;
    }
}

// One tree combine: thread computes output row i of product(L=lm[li], R=lm[ri]).
__device__ __forceinline__ void combine8(float* lm, float* lsh, int li, int ri, int i) {
    const float4* Lb = matp4(lm, li);
    const float4* Rb = matp4(lm, ri);
    float4 la = Lb[i * 2], lb = Lb[i * 2 + 1];
    float4 R[16];
#pragma unroll
    for (int q = 0; q < 16; ++q) R[q] = Rb[q];
    float lk[8] = {la.x, la.y, la.z, la.w, lb.x, lb.y, lb.z, lb.w};
    f2 acc[4];
#pragma unroll
    for (int k = 0; k < 8; ++k) {
        f2 s = splat(lk[k]);
        f2 r0, r1, r2_, r3;
        r0.x = R[2 * k].x;      r0.y = R[2 * k].y;
        r1.x = R[2 * k].z;      r1.y = R[2 * k].w;
        r2_.x = R[2 * k + 1].x; r2_.y = R[2 * k + 1].y;
        r3.x = R[2 * k + 1].z;  r3.y = R[2 * k + 1].w;
        if (k == 0) {
            acc[0] = s * r0; acc[1] = s * r1; acc[2] = s * r2_; acc[3] = s * r3;
        } else {
            acc[0] = fma2(s, r0, acc[0]); acc[1] = fma2(s, r1, acc[1]);
            acc[2] = fma2(s, r2_, acc[2]); acc[3] = fma2(s, r3, acc[3]);
        }
    }
    f2 m2 = max2(max2(acc[0], acc[1]), max2(acc[2], acc[3]));
    float mx = fmaxf(m2.x, m2.y);
    mx = fmaxf(mx, __shfl_xor(mx, 1));
    mx = fmaxf(mx, __shfl_xor(mx, 2));
    mx = fmaxf(mx, __shfl_xor(mx, 4));
    int ex = (__float_as_int(mx) >> 23) & 255;
    float scale = __int_as_float((254 - ex) << 23);
    float ns = lsh[li] + lsh[ri] + (float)(ex - 127);
    f2 sc = splat(scale);
    f2 o0 = acc[0] * sc, o1 = acc[1] * sc, o2 = acc[2] * sc, o3 = acc[3] * sc;
    float4 w0, w1;
    w0.x = o0.x; w0.y = o0.y; w0.z = o1.x; w0.w = o1.y;
    w1.x = o2.x; w1.y = o2.y; w1.z = o3.x; w1.w = o3.y;
    float4* Ob = matp4(lm, li);
    Ob[i * 2] = w0;
    Ob[i * 2 + 1] = w1;
    if (i == 0) lsh[li] = ns;
}

// ---------- single-wave (TPB=64) tree: 64 reg-mats -> slot 0 ----------
__device__ __forceinline__ void hybrid_tree64(f2 P2[K][4], float shift, float* lm, float* lsh) {
    const int t = threadIdx.x;
    const int g = t >> 3;  // group 0..7
    const int i = t & 7;   // row
    if ((t & 1) == 0) {
        store_mat(lm, t >> 1, P2);
        lsh[t >> 1] = shift;
    }
    __syncthreads();
    if (t & 1) {
        const float4* src = matp4(lm, t >> 1);
        float lsv = lsh[t >> 1];
        f2 C[K][4];
#pragma unroll
        for (int r = 0; r < K; ++r) {
            float4 la = src[r * 2], lb = src[r * 2 + 1];
            float lk[8] = {la.x, la.y, la.z, la.w, lb.x, lb.y, lb.z, lb.w};
            f2 q[4];
#pragma unroll
            for (int k = 0; k < 8; ++k) {
                f2 s = splat(lk[k]);
                if (k == 0) {
#pragma unroll
                    for (int jj = 0; jj < 4; ++jj) q[jj] = s * P2[k][jj];
                } else {
#pragma unroll
                    for (int jj = 0; jj < 4; ++jj) q[jj] = fma2(s, P2[k][jj], q[jj]);
                }
            }
#pragma unroll
            for (int jj = 0; jj < 4; ++jj) C[r][jj] = q[jj];
        }
        float ns = shift + lsv;
        renorm2(C, ns);
        store_mat(lm, t >> 1, C);
        lsh[t >> 1] = ns;
    }
    __syncthreads();
    // 32 mats: levels c=16,8,4,2,1 (all wave-internal)
    combine8(lm, lsh, 2 * g, 2 * g + 1, i);
    combine8(lm, lsh, 2 * (g + 8), 2 * (g + 8) + 1, i);
    __syncthreads();
    combine8(lm, lsh, 4 * g, 4 * g + 2, i);
    __syncthreads();
    if (g < 4) combine8(lm, lsh, 8 * g, 8 * g + 4, i);
    __syncthreads();
    if (g < 2) combine8(lm, lsh, 16 * g, 16 * g + 8, i);
    __syncthreads();
    if (g < 1) combine8(lm, lsh, 0, 16, i);
    __syncthreads();
}

// ---------- 256-thread tree (mid stage): 128 LDS mats -> slot 0 ----------
__device__ __forceinline__ void tree_levels256(float* lm, float* lsh) {
    const int g = threadIdx.x >> 3; // group 0..31
    const int i = threadIdx.x & 7;  // output row
#pragma unroll 1
    for (int lvl = 1; lvl <= 3; ++lvl) {
        const int c = 64 >> (lvl - 1);
        const int S = 1 << (lvl - 1);
#pragma unroll 1
        for (int m = g; m < c; m += 32) combine8(lm, lsh, 2 * m * S, 2 * m * S + S, i);
        __syncthreads();
    }
    if (threadIdx.x < 64) {
#pragma unroll 1
        for (int lvl = 4; lvl <= 7; ++lvl) {
            const int c = 64 >> (lvl - 1); // 8,4,2,1
            const int S = 1 << (lvl - 1);
            if (g < c) combine8(lm, lsh, 2 * g * S, 2 * g * S + S, i);
            asm volatile("s_waitcnt lgkmcnt(0)" ::: "memory");
        }
    }
}

// packed emission: e2[4] = exp2(em - max), returns max (state pairs in f2)
__device__ __forceinline__ float emit_e2(const f2 ca2[4], const f2 cb2[4][4],
                                         const f2 cc2[4][4], float4 x, f2 e2[4]) {
    f2 x0 = splat(x.x), x1 = splat(x.y), x2 = splat(x.z), x3 = splat(x.w);
    f2 em2[4];
#pragma unroll
    for (int jj = 0; jj < 4; ++jj) {
        f2 t = ca2[jj];
        t = fma2(fma2(cc2[0][jj], x0, cb2[0][jj]), x0, t);
        t = fma2(fma2(cc2[1][jj], x1, cb2[1][jj]), x1, t);
        t = fma2(fma2(cc2[2][jj], x2, cb2[2][jj]), x2, t);
        t = fma2(fma2(cc2[3][jj], x3, cb2[3][jj]), x3, t);
        em2[jj] = t;
    }
    f2 m2 = max2(max2(em2[0], em2[1]), max2(em2[2], em2[3]));
    float me = fmaxf(m2.x, m2.y);
#pragma unroll
    for (int jj = 0; jj < 4; ++jj) {
        e2[jj].x = exp2_raw(em2[jj].x - me);
        e2[jj].y = exp2_raw(em2[jj].y - me);
    }
    return me;
}

// 64-thread parallel setup (keeps main's consts uniform -> SGPR); zeroes ticket
__global__ void hmm_setup(const float* __restrict__ x,
                          const float* __restrict__ ut,
                          const float* __restrict__ up,
                          const float* __restrict__ mn,
                          const float* __restrict__ lsd,
                          float* __restrict__ ws) {
    const int lane = threadIdx.x;
    const float L2PI = 1.83787706640934548356f;
    const float LOG2E = 1.44269504088896340736f;

    if (lane == 0) reinterpret_cast<unsigned*>(ws + 152)[0] = 0u; // ticket

    float v = ut[lane];
    float m = v;
    m = fmaxf(m, __shfl_xor(m, 1));
    m = fmaxf(m, __shfl_xor(m, 2));
    m = fmaxf(m, __shfl_xor(m, 4));
    float e = expf(v - m);
    float s = e;
    s += __shfl_xor(s, 1); s += __shfl_xor(s, 2); s += __shfl_xor(s, 4);
    ws[lane] = e / s;

    float pv = up[lane & 7];
    float pm = pv;
    pm = fmaxf(pm, __shfl_xor(pm, 1));
    pm = fmaxf(pm, __shfl_xor(pm, 2));
    pm = fmaxf(pm, __shfl_xor(pm, 4));
    float pe = expf(pv - pm);
    float ps = pe;
    ps += __shfl_xor(ps, 1); ps += __shfl_xor(ps, 2); ps += __shfl_xor(ps, 4);
    float pival = pe / ps;

    int k = (lane & 31) >> 2, d = lane & 3;
    float lv = lsd[k * D + d];
    float mu = mn[k * D + d];
    float iv = expf(-2.f * lv);
    float bn = mu * iv;
    float cn = -0.5f * iv;
    float aterm = -0.5f * L2PI - lv - 0.5f * mu * mu * iv;
    float ak = aterm;
    ak += __shfl_xor(ak, 1); ak += __shfl_xor(ak, 2);
    if (lane < 32) {
        ws[72 + lane]  = bn * LOG2E;
        ws[104 + lane] = cn * LOG2E;
        if (d == 0) ws[64 + k] = ak * LOG2E;
    }

    float xd = x[d];
    float part = (cn * xd + bn) * xd + aterm;
    part += __shfl_xor(part, 1); part += __shfl_xor(part, 2);
    float pik = __shfl(pival, k);
    if (lane < 32 && d == 0) ws[136 + k] = pik * expf(part);
}

__global__ __launch_bounds__(TPB) void hmm_main(const float* __restrict__ x,
                                                const float* __restrict__ cst,
                                                float* __restrict__ bp,
                                                float* __restrict__ bs) {
    __shared__ __align__(16) float lm[32 * 76];  // 9.7 KB -> up to 16 blocks/CU
    __shared__ float lsh[32];
    const int t = threadIdx.x;
    const int tid = blockIdx.x * TPB + t;

    float Tr[K][K]; // scalar view (uniform -> SGPR)
#pragma unroll
    for (int i = 0; i < K; ++i)
#pragma unroll
        for (int j = 0; j < K; ++j) Tr[i][j] = cst[i * K + j];
    f2 Tr2[K][4];   // packed column-pair view
#pragma unroll
    for (int i = 0; i < K; ++i)
#pragma unroll
        for (int jj = 0; jj < 4; ++jj) { Tr2[i][jj].x = Tr[i][2 * jj]; Tr2[i][jj].y = Tr[i][2 * jj + 1]; }

    f2 ca2[4], cb2[4][4], cc2[4][4]; // [d][state-pair]
#pragma unroll
    for (int jj = 0; jj < 4; ++jj) {
        ca2[jj].x = cst[64 + 2 * jj]; ca2[jj].y = cst[64 + 2 * jj + 1];
#pragma unroll
        for (int d = 0; d < 4; ++d) {
            cb2[d][jj].x = cst[72 + (2 * jj) * 4 + d];  cb2[d][jj].y = cst[72 + (2 * jj + 1) * 4 + d];
            cc2[d][jj].x = cst[104 + (2 * jj) * 4 + d]; cc2[d][jj].y = cst[104 + (2 * jj + 1) * 4 + d];
        }
    }

    // full-chunk register prefetch: one latency exposure per chunk
    const float4* xv = reinterpret_cast<const float4*>(x) + (size_t)tid * CHUNK;
    float4 xr[CHUNK];
#pragma unroll
    for (int q = 0; q < CHUNK; ++q) xr[q] = xv[q];

    // Chunk transfer = Tr*S0*S1*S2*S3, S=(D_a·Tr·D_b); T packed as f2[8][4]
    f2 T2[K][4];
    float shift;
    {
        f2 eB[4];
        float meB = emit_e2(ca2, cb2, cc2, xr[1], eB);
        if (tid == 0) {
#pragma unroll
            for (int i = 0; i < K; ++i) {
                f2 a0 = splat(cst[136 + i]);
#pragma unroll
                for (int jj = 0; jj < 4; ++jj) T2[i][jj] = a0 * Tr2[i][jj] * eB[jj];
            }
            shift = meB;
        } else {
            f2 eA[4];
            float meA = emit_e2(ca2, cb2, cc2, xr[0], eA);
#pragma unroll
            for (int i = 0; i < K; ++i) {
                f2 ei = splat((i & 1) ? eA[i >> 1].y : eA[i >> 1].x);
#pragma unroll
                for (int jj = 0; jj < 4; ++jj) T2[i][jj] = ei * Tr2[i][jj] * eB[jj];
            }
            shift = meA + meB;
        }
    }

#pragma unroll
    for (int p = 1; p < 4; ++p) {
        f2 eA[4], eB[4];
        float meA = emit_e2(ca2, cb2, cc2, xr[2 * p], eA);
        float meB = emit_e2(ca2, cb2, cc2, xr[2 * p + 1], eB);
        shift += meA + meB;
        // T <- ((T .col eA) * Tr) .col eB, row-wise in place
#pragma unroll
        for (int i = 0; i < K; ++i) {
            f2 r2[4];
#pragma unroll
            for (int kk = 0; kk < 4; ++kk) r2[kk] = T2[i][kk] * eA[kk];
            f2 u[4];
#pragma unroll
            for (int jj = 0; jj < 4; ++jj) u[jj] = splat(r2[0].x) * Tr2[0][jj];
#pragma unroll
            for (int k = 1; k < 8; ++k) {
                f2 rk = splat((k & 1) ? r2[k >> 1].y : r2[k >> 1].x);
#pragma unroll
                for (int jj = 0; jj < 4; ++jj) u[jj] = fma2(rk, Tr2[k][jj], u[jj]);
            }
#pragma unroll
            for (int jj = 0; jj < 4; ++jj) T2[i][jj] = u[jj] * eB[jj];
        }
    }

    if (tid != 0) {
        // T <- Tr * T, column-pair in place
#pragma unroll
        for (int jj = 0; jj < 4; ++jj) {
            f2 c[K];
#pragma unroll
            for (int k = 0; k < K; ++k) c[k] = T2[k][jj];
#pragma unroll
            for (int i = 0; i < K; ++i) {
                f2 a = splat(Tr[i][0]) * c[0];
#pragma unroll
                for (int k = 1; k < K; ++k) a = fma2(splat(Tr[i][k]), c[k], a);
                T2[i][jj] = a;
            }
        }
    }

    renorm2(T2, shift);

    hybrid_tree64(T2, shift, lm, lsh);

    // publish block partial, transposed per-span for coalesced mid reads:
    // float j of matrix m -> bp[s*8192 + (j>>2)*512 + ml*4 + (j&3)], s=m>>7, ml=m&127
    {
        const int s = blockIdx.x >> 7;
        const int ml = blockIdx.x & 127;
        bp[(size_t)s * 8192 + (size_t)(t >> 2) * 512 + ml * 4 + (t & 3)] = lm[t];
        if (t == 0) bs[s * 128 + ml] = lsh[0];
    }
}

// Stage 2 (+fused finale): NMID=32 blocks; block s tree-reduces its span's 128
// matrices (coalesced loads). Last-arriving block (agent-scope ticket, 32 RMWs
// total -- cheap at this scale, unlike round-4's 4096) reduces the 32 partials
// and writes out[0].
__global__ __launch_bounds__(256) void hmm_mid(const float* __restrict__ bp,
                                               const float* __restrict__ bs,
                                               float* __restrict__ bp2,
                                               float* __restrict__ bs2,
                                               unsigned* __restrict__ cnt,
                                               float* __restrict__ out) {
    __shared__ __align__(16) float lm[128 * 76];
    __shared__ float lsh[128];
    __shared__ int lastflag;
    const int t = threadIdx.x;
    const int s = blockIdx.x;
    const float4* bp4 = reinterpret_cast<const float4*>(bp) + (size_t)s * 2048;

    // 8 coalesced 1KB wave-loads; scatter into LDS matrix slots
#pragma unroll
    for (int k = 0; k < 8; ++k) {
        float4 v = bp4[k * 256 + t];
        int q = 2 * k + (t >> 7);     // float4 index 0..15
        int ml = t & 127;             // matrix slot
        matp4(lm, ml)[q] = v;
    }
    if (t < 128) lsh[t] = bs[s * 128 + t];
    __syncthreads();

    tree_levels256(lm, lsh);

    // publish partial with agent-scope stores + release ticket (round-3/4 pattern)
    if (t == 0) {
        const float* l0 = lm; // slot 0 contiguous at lm[0..63]
#pragma unroll
        for (int q = 0; q < 64; ++q)
            __hip_atomic_store(&bp2[s * 64 + q], l0[q], __ATOMIC_RELAXED, __HIP_MEMORY_SCOPE_AGENT);
        __hip_atomic_store(&bs2[s], lsh[0], __ATOMIC_RELAXED, __HIP_MEMORY_SCOPE_AGENT);
        __threadfence();
        unsigned tk = __hip_atomic_fetch_add(cnt, 1u, __ATOMIC_ACQ_REL, __HIP_MEMORY_SCOPE_AGENT);
        lastflag = (tk == NMID - 1) ? 1 : 0;
    }
    __syncthreads();
    if (!lastflag) return;

    // ----- last block: reduce the NMID=32 partials (round-9 final body) -----
    __threadfence(); // acquire side
    if (t < 128) {
#pragma unroll
        for (int j = 0; j < 4; ++j) {
            int f = t * 4 + j;           // float4 index into bp2 (0..511)
            int mat = f >> 4, off = f & 15;
            float4 v;
            v.x = __hip_atomic_load(&bp2[f * 4 + 0], __ATOMIC_RELAXED, __HIP_MEMORY_SCOPE_AGENT);
            v.y = __hip_atomic_load(&bp2[f * 4 + 1], __ATOMIC_RELAXED, __HIP_MEMORY_SCOPE_AGENT);
            v.z = __hip_atomic_load(&bp2[f * 4 + 2], __ATOMIC_RELAXED, __HIP_MEMORY_SCOPE_AGENT);
            v.w = __hip_atomic_load(&bp2[f * 4 + 3], __ATOMIC_RELAXED, __HIP_MEMORY_SCOPE_AGENT);
            matp4(lm, mat)[off] = v;
        }
        if (t < 32) lsh[t] = __hip_atomic_load(&bs2[t], __ATOMIC_RELAXED, __HIP_MEMORY_SCOPE_AGENT);
    }
    __syncthreads();

    const int g = t >> 3; // group
    const int i = t & 7;  // row
    if (t < 128) combine8(lm, lsh, 2 * g, 2 * g + 1, i);              // 32 -> 16
    __syncthreads();
    if (t < 64)  combine8(lm, lsh, 4 * g, 4 * g + 2, i);              // 16 -> 8
    __syncthreads();
    if (t < 32)  combine8(lm, lsh, 8 * g, 8 * g + 4, i);              // 8 -> 4
    __syncthreads();
    if (t < 16)  combine8(lm, lsh, 16 * g, 16 * g + 8, i);            // 4 -> 2
    __syncthreads();
    if (t < 8)   combine8(lm, lsh, 0, 16, i);                         // 2 -> 1
    __syncthreads();

    if (t == 0) {
        double sdbl = 0.0;
#pragma unroll
        for (int q = 0; q < 64; ++q) sdbl += (double)lm[q];
        out[0] = (float)(log(sdbl) + (double)lsh[0] * 0.69314718055994530942);
    }
}

extern "C" void kernel_launch(void* const* d_in, const int* in_sizes, int n_in,
                              void* d_out, int out_size, void* d_ws, size_t ws_size,
                              hipStream_t stream) {
    (void)in_sizes; (void)n_in; (void)out_size; (void)ws_size;
    const float* x  = (const float*)d_in[0];
    const float* ut = (const float*)d_in[1];
    const float* up = (const float*)d_in[2];
    const float* mn = (const float*)d_in[3];
    const float* ls = (const float*)d_in[4];
    float* ws  = (float*)d_ws;
    float* out = (float*)d_out;
    float* bp  = ws + 256;
    float* bs  = bp + (size_t)NBLK * 64;
    float* bp2 = bs + NBLK;
    float* bs2 = bp2 + (size_t)NMID * 64;
    unsigned* cnt = reinterpret_cast<unsigned*>(ws + 152);

    hmm_setup<<<1, 64, 0, stream>>>(x, ut, up, mn, ls, ws);
    hmm_main<<<NBLK, TPB, 0, stream>>>(x, ws, bp, bs);
    hmm_mid<<<NMID, 256, 0, stream>>>(bp, bs, bp2, bs2, cnt, out);
}

// Round 12
// 117.565 us; speedup vs baseline: 1.0089x; 1.0089x over previous
//
#include <hip/hip_runtime.h>
#include <math.h>

#define T_LEN 2097152
#define K 8
#define D 4
#define CHUNK 16
#define TPB 64                         // single-wave workgroups
#define NBLK (T_LEN / (CHUNK * TPB))   // 2048 blocks
#define MS4 19                         // float4 stride per LDS matrix slot (76 floats, 16B-aligned)
#define NMID 16                        // stage-2 blocks, each reduces 128 mats
#define MPM (NBLK / NMID)              // 128 matrices per mid block

typedef float f2 __attribute__((ext_vector_type(2)));

__device__ __forceinline__ f2 fma2(f2 a, f2 b, f2 c) { return __builtin_elementwise_fma(a, b, c); }
__device__ __forceinline__ f2 max2(f2 a, f2 b) { return __builtin_elementwise_max(a, b); }
__device__ __forceinline__ f2 splat(float s) { f2 r; r.x = s; r.y = s; return r; }

// raw hardware exp2: skips the denorm-range fixup exp2f carries.
// Inputs are max-subtracted (<= 0); sub-denormal results are dead after renorm.
__device__ __forceinline__ float exp2_raw(float x) {
    float r;
    asm("v_exp_f32 %0, %1" : "=v"(r) : "v"(x));
    return r;
}

// ws layout (floats): [0..63] Tr; [64..71] a; [72..103] b; [104..135] c; [136..143] alpha0
// [256..) bp (NBLK*64, transposed per-span), bs (NBLK, transposed), bp2 (NMID*64), bs2 (NMID)
//
// bp layout: matrix m -> span s = m>>7 (0..15), ml = m&127. float4 q of m lives at
// float4-index s*2048 + q*128 + ml. Mid block s reads float4s [s*2048 + k*256 + t]
// for k=0..7 -- lane-consecutive, fully coalesced. bs[s*128 + ml].

// LDS matrix slot li: float4 base = li*19 + ((li>>1)&3)  (bank-spreading swizzle,
// keeps all rows 16B-aligned; offset+63 <= 75 < 76 so slots never overlap)
__device__ __forceinline__ float4* matp4(float* lm, int li) {
    return reinterpret_cast<float4*>(lm) + li * MS4 + ((li >> 1) & 3);
}

__device__ __forceinline__ void renorm2(f2 M[K][4], float& shift) {
    f2 m2 = max2(max2(M[0][0], M[0][1]), max2(M[0][2], M[0][3]));
#pragma unroll
    for (int i = 1; i < K; ++i)
        m2 = max2(m2, max2(max2(M[i][0], M[i][1]), max2(M[i][2], M[i][3])));
    float mx = fmaxf(m2.x, m2.y);
    int ex = (__float_as_int(mx) >> 23) & 255;
    float scale = __int_as_float((254 - ex) << 23); // 2^(127-ex)
    shift += (float)(ex - 127);
    f2 sc = splat(scale);
#pragma unroll
    for (int i = 0; i < K; ++i)
#pragma unroll
        for (int jj = 0; jj < 4; ++jj) M[i][jj] = M[i][jj] * sc;
}

__device__ __forceinline__ void store_mat(float* lm, int li, const f2 M[K][4]) {
    float4* dst = matp4(lm, li);
#pragma unroll
    for (int i = 0; i < K; ++i) {
        float4 w0, w1;
        w0.x = M[i][0].x; w0.y = M[i][0].y; w0.z = M[i][1].x; w0.w = M[i][1].y;
        w1.x = M[i][2].x; w1.y = M[i][2].y; w1.z = M[i][3].x; w1.w = M[i][3].y;
        dst[i * 2] = w0;
        dst[i * 2 + 1] = w1;
    }
}

// One tree combine: thread computes output row i of product(L=lm[li], R=lm[ri]).
__device__ __forceinline__ void combine8(float* lm, float* lsh, int li, int ri, int i) {
    const float4* Lb = matp4(lm, li);
    const float4* Rb = matp4(lm, ri);
    float4 la = Lb[i * 2], lb = Lb[i * 2 + 1];
    float4 R[16];
#pragma unroll
    for (int q = 0; q < 16; ++q) R[q] = Rb[q];
    float lk[8] = {la.x, la.y, la.z, la.w, lb.x, lb.y, lb.z, lb.w};
    f2 acc[4];
#pragma unroll
    for (int k = 0; k < 8; ++k) {
        f2 s = splat(lk[k]);
        f2 r0, r1, r2_, r3;
        r0.x = R[2 * k].x;      r0.y = R[2 * k].y;
        r1.x = R[2 * k].z;      r1.y = R[2 * k].w;
        r2_.x = R[2 * k + 1].x; r2_.y = R[2 * k + 1].y;
        r3.x = R[2 * k + 1].z;  r3.y = R[2 * k + 1].w;
        if (k == 0) {
            acc[0] = s * r0; acc[1] = s * r1; acc[2] = s * r2_; acc[3] = s * r3;
        } else {
            acc[0] = fma2(s, r0, acc[0]); acc[1] = fma2(s, r1, acc[1]);
            acc[2] = fma2(s, r2_, acc[2]); acc[3] = fma2(s, r3, acc[3]);
        }
    }
    f2 m2 = max2(max2(acc[0], acc[1]), max2(acc[2], acc[3]));
    float mx = fmaxf(m2.x, m2.y);
    mx = fmaxf(mx, __shfl_xor(mx, 1));
    mx = fmaxf(mx, __shfl_xor(mx, 2));
    mx = fmaxf(mx, __shfl_xor(mx, 4));
    int ex = (__float_as_int(mx) >> 23) & 255;
    float scale = __int_as_float((254 - ex) << 23);
    float ns = lsh[li] + lsh[ri] + (float)(ex - 127);
    f2 sc = splat(scale);
    f2 o0 = acc[0] * sc, o1 = acc[1] * sc, o2 = acc[2] * sc, o3 = acc[3] * sc;
    float4 w0, w1;
    w0.x = o0.x; w0.y = o0.y; w0.z = o1.x; w0.w = o1.y;
    w1.x = o2.x; w1.y = o2.y; w1.z = o3.x; w1.w = o3.y;
    float4* Ob = matp4(lm, li);
    Ob[i * 2] = w0;
    Ob[i * 2 + 1] = w1;
    if (i == 0) lsh[li] = ns;
}

// ---------- single-wave (TPB=64) tree: 64 reg-mats -> slot 0 ----------
__device__ __forceinline__ void hybrid_tree64(f2 P2[K][4], float shift, float* lm, float* lsh) {
    const int t = threadIdx.x;
    const int g = t >> 3;  // group 0..7
    const int i = t & 7;   // row
    if ((t & 1) == 0) {
        store_mat(lm, t >> 1, P2);
        lsh[t >> 1] = shift;
    }
    __syncthreads();
    if (t & 1) {
        const float4* src = matp4(lm, t >> 1);
        float lsv = lsh[t >> 1];
        f2 C[K][4];
#pragma unroll
        for (int r = 0; r < K; ++r) {
            float4 la = src[r * 2], lb = src[r * 2 + 1];
            float lk[8] = {la.x, la.y, la.z, la.w, lb.x, lb.y, lb.z, lb.w};
            f2 q[4];
#pragma unroll
            for (int k = 0; k < 8; ++k) {
                f2 s = splat(lk[k]);
                if (k == 0) {
#pragma unroll
                    for (int jj = 0; jj < 4; ++jj) q[jj] = s * P2[k][jj];
                } else {
#pragma unroll
                    for (int jj = 0; jj < 4; ++jj) q[jj] = fma2(s, P2[k][jj], q[jj]);
                }
            }
#pragma unroll
            for (int jj = 0; jj < 4; ++jj) C[r][jj] = q[jj];
        }
        float ns = shift + lsv;
        renorm2(C, ns);
        store_mat(lm, t >> 1, C);
        lsh[t >> 1] = ns;
    }
    __syncthreads();
    // 32 mats: levels c=16,8,4,2,1 (all wave-internal)
    combine8(lm, lsh, 2 * g, 2 * g + 1, i);
    combine8(lm, lsh, 2 * (g + 8), 2 * (g + 8) + 1, i);
    __syncthreads();
    combine8(lm, lsh, 4 * g, 4 * g + 2, i);
    __syncthreads();
    if (g < 4) combine8(lm, lsh, 8 * g, 8 * g + 4, i);
    __syncthreads();
    if (g < 2) combine8(lm, lsh, 16 * g, 16 * g + 8, i);
    __syncthreads();
    if (g < 1) combine8(lm, lsh, 0, 16, i);
    __syncthreads();
}

// ---------- 256-thread tree (mid stage): 128 LDS mats -> slot 0 ----------
__device__ __forceinline__ void tree_levels256(float* lm, float* lsh) {
    const int g = threadIdx.x >> 3; // group 0..31
    const int i = threadIdx.x & 7;  // output row
#pragma unroll 1
    for (int lvl = 1; lvl <= 3; ++lvl) {
        const int c = 64 >> (lvl - 1);
        const int S = 1 << (lvl - 1);
#pragma unroll 1
        for (int m = g; m < c; m += 32) combine8(lm, lsh, 2 * m * S, 2 * m * S + S, i);
        __syncthreads();
    }
    if (threadIdx.x < 64) {
#pragma unroll 1
        for (int lvl = 4; lvl <= 7; ++lvl) {
            const int c = 64 >> (lvl - 1); // 8,4,2,1
            const int S = 1 << (lvl - 1);
            if (g < c) combine8(lm, lsh, 2 * g * S, 2 * g * S + S, i);
            asm volatile("s_waitcnt lgkmcnt(0)" ::: "memory");
        }
    }
}

// packed emission: e2[4] = exp2(em - max), returns max (state pairs in f2)
__device__ __forceinline__ float emit_e2(const f2 ca2[4], const f2 cb2[4][4],
                                         const f2 cc2[4][4], float4 x, f2 e2[4]) {
    f2 x0 = splat(x.x), x1 = splat(x.y), x2 = splat(x.z), x3 = splat(x.w);
    f2 em2[4];
#pragma unroll
    for (int jj = 0; jj < 4; ++jj) {
        f2 t = ca2[jj];
        t = fma2(fma2(cc2[0][jj], x0, cb2[0][jj]), x0, t);
        t = fma2(fma2(cc2[1][jj], x1, cb2[1][jj]), x1, t);
        t = fma2(fma2(cc2[2][jj], x2, cb2[2][jj]), x2, t);
        t = fma2(fma2(cc2[3][jj], x3, cb2[3][jj]), x3, t);
        em2[jj] = t;
    }
    f2 m2 = max2(max2(em2[0], em2[1]), max2(em2[2], em2[3]));
    float me = fmaxf(m2.x, m2.y);
#pragma unroll
    for (int jj = 0; jj < 4; ++jj) {
        e2[jj].x = exp2_raw(em2[jj].x - me);
        e2[jj].y = exp2_raw(em2[jj].y - me);
    }
    return me;
}

// 64-thread parallel setup (keeps main's consts uniform -> SGPR)
__global__ void hmm_setup(const float* __restrict__ x,
                          const float* __restrict__ ut,
                          const float* __restrict__ up,
                          const float* __restrict__ mn,
                          const float* __restrict__ lsd,
                          float* __restrict__ ws) {
    const int lane = threadIdx.x;
    const float L2PI = 1.83787706640934548356f;
    const float LOG2E = 1.44269504088896340736f;

    float v = ut[lane];
    float m = v;
    m = fmaxf(m, __shfl_xor(m, 1));
    m = fmaxf(m, __shfl_xor(m, 2));
    m = fmaxf(m, __shfl_xor(m, 4));
    float e = expf(v - m);
    float s = e;
    s += __shfl_xor(s, 1); s += __shfl_xor(s, 2); s += __shfl_xor(s, 4);
    ws[lane] = e / s;

    float pv = up[lane & 7];
    float pm = pv;
    pm = fmaxf(pm, __shfl_xor(pm, 1));
    pm = fmaxf(pm, __shfl_xor(pm, 2));
    pm = fmaxf(pm, __shfl_xor(pm, 4));
    float pe = expf(pv - pm);
    float ps = pe;
    ps += __shfl_xor(ps, 1); ps += __shfl_xor(ps, 2); ps += __shfl_xor(ps, 4);
    float pival = pe / ps;

    int k = (lane & 31) >> 2, d = lane & 3;
    float lv = lsd[k * D + d];
    float mu = mn[k * D + d];
    float iv = expf(-2.f * lv);
    float bn = mu * iv;
    float cn = -0.5f * iv;
    float aterm = -0.5f * L2PI - lv - 0.5f * mu * mu * iv;
    float ak = aterm;
    ak += __shfl_xor(ak, 1); ak += __shfl_xor(ak, 2);
    if (lane < 32) {
        ws[72 + lane]  = bn * LOG2E;
        ws[104 + lane] = cn * LOG2E;
        if (d == 0) ws[64 + k] = ak * LOG2E;
    }

    float xd = x[d];
    float part = (cn * xd + bn) * xd + aterm;
    part += __shfl_xor(part, 1); part += __shfl_xor(part, 2);
    float pik = __shfl(pival, k);
    if (lane < 32 && d == 0) ws[136 + k] = pik * expf(part);
}

__global__ __launch_bounds__(TPB) void hmm_main(const float* __restrict__ x,
                                                const float* __restrict__ cst,
                                                float* __restrict__ bp,
                                                float* __restrict__ bs) {
    __shared__ __align__(16) float lm[32 * 76];  // 9.7 KB
    __shared__ float lsh[32];
    const int t = threadIdx.x;
    const int tid = blockIdx.x * TPB + t;

    float Tr[K][K]; // scalar view (uniform -> SGPR)
#pragma unroll
    for (int i = 0; i < K; ++i)
#pragma unroll
        for (int j = 0; j < K; ++j) Tr[i][j] = cst[i * K + j];
    f2 Tr2[K][4];   // packed column-pair view
#pragma unroll
    for (int i = 0; i < K; ++i)
#pragma unroll
        for (int jj = 0; jj < 4; ++jj) { Tr2[i][jj].x = Tr[i][2 * jj]; Tr2[i][jj].y = Tr[i][2 * jj + 1]; }

    f2 ca2[4], cb2[4][4], cc2[4][4]; // [d][state-pair]
#pragma unroll
    for (int jj = 0; jj < 4; ++jj) {
        ca2[jj].x = cst[64 + 2 * jj]; ca2[jj].y = cst[64 + 2 * jj + 1];
#pragma unroll
        for (int d = 0; d < 4; ++d) {
            cb2[d][jj].x = cst[72 + (2 * jj) * 4 + d];  cb2[d][jj].y = cst[72 + (2 * jj + 1) * 4 + d];
            cc2[d][jj].x = cst[104 + (2 * jj) * 4 + d]; cc2[d][jj].y = cst[104 + (2 * jj + 1) * 4 + d];
        }
    }

    // full-chunk register prefetch: one latency exposure per chunk (16 x float4)
    const float4* xv = reinterpret_cast<const float4*>(x) + (size_t)tid * CHUNK;
    float4 xr[CHUNK];
#pragma unroll
    for (int q = 0; q < CHUNK; ++q) xr[q] = xv[q];

    // Chunk transfer over 16 steps; T packed as f2[8][4]
    f2 T2[K][4];
    float shift;
    {
        f2 eB[4];
        float meB = emit_e2(ca2, cb2, cc2, xr[1], eB);
        if (tid == 0) {
#pragma unroll
            for (int i = 0; i < K; ++i) {
                f2 a0 = splat(cst[136 + i]);
#pragma unroll
                for (int jj = 0; jj < 4; ++jj) T2[i][jj] = a0 * Tr2[i][jj] * eB[jj];
            }
            shift = meB;
        } else {
            f2 eA[4];
            float meA = emit_e2(ca2, cb2, cc2, xr[0], eA);
#pragma unroll
            for (int i = 0; i < K; ++i) {
                f2 ei = splat((i & 1) ? eA[i >> 1].y : eA[i >> 1].x);
#pragma unroll
                for (int jj = 0; jj < 4; ++jj) T2[i][jj] = ei * Tr2[i][jj] * eB[jj];
            }
            shift = meA + meB;
        }
    }

#pragma unroll
    for (int p = 1; p < CHUNK / 2; ++p) {
        f2 eA[4], eB[4];
        float meA = emit_e2(ca2, cb2, cc2, xr[2 * p], eA);
        float meB = emit_e2(ca2, cb2, cc2, xr[2 * p + 1], eB);
        shift += meA + meB;
        // T <- ((T .col eA) * Tr) .col eB, row-wise in place
#pragma unroll
        for (int i = 0; i < K; ++i) {
            f2 r2[4];
#pragma unroll
            for (int kk = 0; kk < 4; ++kk) r2[kk] = T2[i][kk] * eA[kk];
            f2 u[4];
#pragma unroll
            for (int jj = 0; jj < 4; ++jj) u[jj] = splat(r2[0].x) * Tr2[0][jj];
#pragma unroll
            for (int k = 1; k < 8; ++k) {
                f2 rk = splat((k & 1) ? r2[k >> 1].y : r2[k >> 1].x);
#pragma unroll
                for (int jj = 0; jj < 4; ++jj) u[jj] = fma2(rk, Tr2[k][jj], u[jj]);
            }
#pragma unroll
            for (int jj = 0; jj < 4; ++jj) T2[i][jj] = u[jj] * eB[jj];
        }
        // mid-chunk renorm: keeps magnitude envelope identical to CHUNK=8
        if (p == 3) renorm2(T2, shift);
    }

    if (tid != 0) {
        // T <- Tr * T, column-pair in place
#pragma unroll
        for (int jj = 0; jj < 4; ++jj) {
            f2 c[K];
#pragma unroll
            for (int k = 0; k < K; ++k) c[k] = T2[k][jj];
#pragma unroll
            for (int i = 0; i < K; ++i) {
                f2 a = splat(Tr[i][0]) * c[0];
#pragma unroll
                for (int k = 1; k < K; ++k) a = fma2(splat(Tr[i][k]), c[k], a);
                T2[i][jj] = a;
            }
        }
    }

    renorm2(T2, shift);

    hybrid_tree64(T2, shift, lm, lsh);

    // publish block partial, transposed per-span for coalesced mid reads:
    // float j of matrix m -> bp[s*8192 + (j>>2)*512 + ml*4 + (j&3)], s=m>>7, ml=m&127
    {
        const int s = blockIdx.x >> 7;
        const int ml = blockIdx.x & 127;
        bp[(size_t)s * 8192 + (size_t)(t >> 2) * 512 + ml * 4 + (t & 3)] = lm[t];
        if (t == 0) bs[s * 128 + ml] = lsh[0];
    }
}

// Stage 2: NMID=16 blocks; block s tree-reduces its span's 128 matrices.
// Loads are fully lane-coalesced thanks to the transposed bp layout.
__global__ __launch_bounds__(256) void hmm_mid(const float* __restrict__ bp,
                                               const float* __restrict__ bs,
                                               float* __restrict__ bp2,
                                               float* __restrict__ bs2) {
    __shared__ __align__(16) float lm[128 * 76];
    __shared__ float lsh[128];
    const int t = threadIdx.x;
    const int s = blockIdx.x;
    const float4* bp4 = reinterpret_cast<const float4*>(bp) + (size_t)s * 2048;

    // 8 coalesced 1KB wave-loads; scatter into LDS matrix slots
#pragma unroll
    for (int k = 0; k < 8; ++k) {
        float4 v = bp4[k * 256 + t];
        int q = 2 * k + (t >> 7);     // float4 index 0..15
        int ml = t & 127;             // matrix slot
        matp4(lm, ml)[q] = v;
    }
    if (t < 128) lsh[t] = bs[s * 128 + t];
    __syncthreads();

    tree_levels256(lm, lsh);

    if (t == 0) {
        float4* o4 = reinterpret_cast<float4*>(bp2 + (size_t)s * 64);
        const float4* l4 = reinterpret_cast<const float4*>(lm); // slot 0 contiguous
#pragma unroll
        for (int q = 0; q < 16; ++q) o4[q] = l4[q];
        bs2[s] = lsh[0];
    }
}

// Stage 3: one 128-thread block reduces the NMID=16 partials (4 levels), emits scalar
__global__ __launch_bounds__(128) void hmm_final(const float* __restrict__ bp2,
                                                 const float* __restrict__ bs2,
                                                 float* __restrict__ out) {
    __shared__ __align__(16) float lm[16 * 76];
    __shared__ float lsh[16];
    const int t = threadIdx.x;
    const int g = t >> 3; // group 0..15
    const int i = t & 7;  // row

    // coalesced load of 16*64 floats: thread t moves float4s [2t, 2t+1]
    {
        const float4* src = reinterpret_cast<const float4*>(bp2);
#pragma unroll
        for (int j = 0; j < 2; ++j) {
            int f = t * 2 + j;            // 0..255
            int mat = f >> 4, off = f & 15;
            matp4(lm, mat)[off] = src[f];
        }
    }
    if (t < 16) lsh[t] = bs2[t];
    __syncthreads();

    if (g < 8) combine8(lm, lsh, 2 * g, 2 * g + 1, i);   // 16 -> 8 (groups 0..7 ONLY -- r11 bug fix)
    __syncthreads();
    if (g < 4) combine8(lm, lsh, 4 * g, 4 * g + 2, i);   // 8 -> 4
    __syncthreads();
    if (g < 2) combine8(lm, lsh, 8 * g, 8 * g + 4, i);   // 4 -> 2
    __syncthreads();
    if (g < 1) combine8(lm, lsh, 0, 8, i);               // 2 -> 1
    __syncthreads();

    if (t == 0) {
        double sdbl = 0.0;
#pragma unroll
        for (int q = 0; q < 64; ++q) sdbl += (double)lm[q];
        out[0] = (float)(log(sdbl) + (double)lsh[0] * 0.69314718055994530942);
    }
}

extern "C" void kernel_launch(void* const* d_in, const int* in_sizes, int n_in,
                              void* d_out, int out_size, void* d_ws, size_t ws_size,
                              hipStream_t stream) {
    (void)in_sizes; (void)n_in; (void)out_size; (void)ws_size;
    const float* x  = (const float*)d_in[0];
    const float* ut = (const float*)d_in[1];
    const float* up = (const float*)d_in[2];
    const float* mn = (const float*)d_in[3];
    const float* ls = (const float*)d_in[4];
    float* ws  = (float*)d_ws;
    float* out = (float*)d_out;
    float* bp  = ws + 256;
    float* bs  = bp + (size_t)NBLK * 64;
    float* bp2 = bs + NBLK;
    float* bs2 = bp2 + (size_t)NMID * 64;

    hmm_setup<<<1, 64, 0, stream>>>(x, ut, up, mn, ls, ws);
    hmm_main<<<NBLK, TPB, 0, stream>>>(x, ws, bp, bs);
    hmm_mid<<<NMID, 256, 0, stream>>>(bp, bs, bp2, bs2);
    hmm_final<<<1, 128, 0, stream>>>(bp2, bs2, out);
}

// Round 13
// 116.092 us; speedup vs baseline: 1.0217x; 1.0127x over previous
//
#include <hip/hip_runtime.h>
#include <math.h>

#define T_LEN 2097152
#define K 8
#define D 4
#define CHUNK 8
#define TPB 64                         // single-wave workgroups
#define NBLK (T_LEN / (CHUNK * TPB))   // 4096 blocks
#define MS4 19                         // float4 stride per LDS matrix slot (76 floats, 16B-aligned)
#define NMID 32                        // stage-2 blocks
#define MPM (NBLK / NMID)              // 128 matrices per mid block

typedef float f2 __attribute__((ext_vector_type(2)));

__device__ __forceinline__ f2 fma2(f2 a, f2 b, f2 c) { return __builtin_elementwise_fma(a, b, c); }
__device__ __forceinline__ f2 max2(f2 a, f2 b) { return __builtin_elementwise_max(a, b); }
__device__ __forceinline__ f2 splat(float s) { f2 r; r.x = s; r.y = s; return r; }

// raw hardware exp2: skips the denorm-range fixup exp2f carries.
// Inputs are max-subtracted (<= 0); sub-denormal results are dead after renorm.
__device__ __forceinline__ float exp2_raw(float x) {
    float r;
    asm("v_exp_f32 %0, %1" : "=v"(r) : "v"(x));
    return r;
}

// ws layout (floats): [0..63] Tr; [64..71] a; [72..103] b; [104..135] c; [136..143] alpha0
// [256..) bp (NBLK*64, transposed per-span), bs (NBLK, transposed), bp2 (NMID*64), bs2 (NMID)
//
// bp layout: matrix m -> span s = m>>7 (0..31), ml = m&127. float4 q of m lives at
// float4-index s*2048 + q*128 + ml. Mid block s reads float4s [s*2048 + k*256 + t]
// for k=0..7 -- lane-consecutive, fully coalesced. bs[s*128 + ml].

// LDS matrix slot li: float4 base = li*19 + ((li>>1)&3)  (bank-spreading swizzle,
// keeps all rows 16B-aligned; offset+63 <= 75 < 76 so slots never overlap)
__device__ __forceinline__ float4* matp4(float* lm, int li) {
    return reinterpret_cast<float4*>(lm) + li * MS4 + ((li >> 1) & 3);
}

__device__ __forceinline__ void renorm2(f2 M[K][4], float& shift) {
    f2 m2 = max2(max2(M[0][0], M[0][1]), max2(M[0][2], M[0][3]));
#pragma unroll
    for (int i = 1; i < K; ++i)
        m2 = max2(m2, max2(max2(M[i][0], M[i][1]), max2(M[i][2], M[i][3])));
    float mx = fmaxf(m2.x, m2.y);
    int ex = (__float_as_int(mx) >> 23) & 255;
    float scale = __int_as_float((254 - ex) << 23); // 2^(127-ex)
    shift += (float)(ex - 127);
    f2 sc = splat(scale);
#pragma unroll
    for (int i = 0; i < K; ++i)
#pragma unroll
        for (int jj = 0; jj < 4; ++jj) M[i][jj] = M[i][jj] * sc;
}

__device__ __forceinline__ void store_mat(float* lm, int li, const f2 M[K][4]) {
    float4* dst = matp4(lm, li);
#pragma unroll
    for (int i = 0; i < K; ++i) {
        float4 w0, w1;
        w0.x = M[i][0].x; w0.y = M[i][0].y; w0.z = M[i][1].x; w0.w = M[i][1].y;
        w1.x = M[i][2].x; w1.y = M[i][2].y; w1.z = M[i][3].x; w1.w = M[i][3].y;
        dst[i * 2] = w0;
        dst[i * 2 + 1] = w1;
    }
}

// One tree combine: thread computes output row i of product(L=lm[li], R=lm[ri]).
__device__ __forceinline__ void combine8(float* lm, float* lsh, int li, int ri, int i) {
    const float4* Lb = matp4(lm, li);
    const float4* Rb = matp4(lm, ri);
    float4 la = Lb[i * 2], lb = Lb[i * 2 + 1];
    float4 R[16];
#pragma unroll
    for (int q = 0; q < 16; ++q) R[q] = Rb[q];
    float lk[8] = {la.x, la.y, la.z, la.w, lb.x, lb.y, lb.z, lb.w};
    f2 acc[4];
#pragma unroll
    for (int k = 0; k < 8; ++k) {
        f2 s = splat(lk[k]);
        f2 r0, r1, r2_, r3;
        r0.x = R[2 * k].x;      r0.y = R[2 * k].y;
        r1.x = R[2 * k].z;      r1.y = R[2 * k].w;
        r2_.x = R[2 * k + 1].x; r2_.y = R[2 * k + 1].y;
        r3.x = R[2 * k + 1].z;  r3.y = R[2 * k + 1].w;
        if (k == 0) {
            acc[0] = s * r0; acc[1] = s * r1; acc[2] = s * r2_; acc[3] = s * r3;
        } else {
            acc[0] = fma2(s, r0, acc[0]); acc[1] = fma2(s, r1, acc[1]);
            acc[2] = fma2(s, r2_, acc[2]); acc[3] = fma2(s, r3, acc[3]);
        }
    }
    f2 m2 = max2(max2(acc[0], acc[1]), max2(acc[2], acc[3]));
    float mx = fmaxf(m2.x, m2.y);
    mx = fmaxf(mx, __shfl_xor(mx, 1));
    mx = fmaxf(mx, __shfl_xor(mx, 2));
    mx = fmaxf(mx, __shfl_xor(mx, 4));
    int ex = (__float_as_int(mx) >> 23) & 255;
    float scale = __int_as_float((254 - ex) << 23);
    float ns = lsh[li] + lsh[ri] + (float)(ex - 127);
    f2 sc = splat(scale);
    f2 o0 = acc[0] * sc, o1 = acc[1] * sc, o2 = acc[2] * sc, o3 = acc[3] * sc;
    float4 w0, w1;
    w0.x = o0.x; w0.y = o0.y; w0.z = o1.x; w0.w = o1.y;
    w1.x = o2.x; w1.y = o2.y; w1.z = o3.x; w1.w = o3.y;
    float4* Ob = matp4(lm, li);
    Ob[i * 2] = w0;
    Ob[i * 2 + 1] = w1;
    if (i == 0) lsh[li] = ns;
}

// ---------- single-wave (TPB=64) tree: 64 reg-mats -> slot 0 ----------
__device__ __forceinline__ void hybrid_tree64(f2 P2[K][4], float shift, float* lm, float* lsh) {
    const int t = threadIdx.x;
    const int g = t >> 3;  // group 0..7
    const int i = t & 7;   // row
    if ((t & 1) == 0) {
        store_mat(lm, t >> 1, P2);
        lsh[t >> 1] = shift;
    }
    __syncthreads();
    if (t & 1) {
        const float4* src = matp4(lm, t >> 1);
        float lsv = lsh[t >> 1];
        f2 C[K][4];
#pragma unroll
        for (int r = 0; r < K; ++r) {
            float4 la = src[r * 2], lb = src[r * 2 + 1];
            float lk[8] = {la.x, la.y, la.z, la.w, lb.x, lb.y, lb.z, lb.w};
            f2 q[4];
#pragma unroll
            for (int k = 0; k < 8; ++k) {
                f2 s = splat(lk[k]);
                if (k == 0) {
#pragma unroll
                    for (int jj = 0; jj < 4; ++jj) q[jj] = s * P2[k][jj];
                } else {
#pragma unroll
                    for (int jj = 0; jj < 4; ++jj) q[jj] = fma2(s, P2[k][jj], q[jj]);
                }
            }
#pragma unroll
            for (int jj = 0; jj < 4; ++jj) C[r][jj] = q[jj];
        }
        float ns = shift + lsv;
        renorm2(C, ns);
        store_mat(lm, t >> 1, C);
        lsh[t >> 1] = ns;
    }
    __syncthreads();
    // 32 mats: levels c=16,8,4,2,1 (all wave-internal)
    combine8(lm, lsh, 2 * g, 2 * g + 1, i);
    combine8(lm, lsh, 2 * (g + 8), 2 * (g + 8) + 1, i);
    __syncthreads();
    combine8(lm, lsh, 4 * g, 4 * g + 2, i);
    __syncthreads();
    if (g < 4) combine8(lm, lsh, 8 * g, 8 * g + 4, i);
    __syncthreads();
    if (g < 2) combine8(lm, lsh, 16 * g, 16 * g + 8, i);
    __syncthreads();
    if (g < 1) combine8(lm, lsh, 0, 16, i);
    __syncthreads();
}

// ---------- 256-thread tree (mid stage): 128 LDS mats -> slot 0 ----------
__device__ __forceinline__ void tree_levels256(float* lm, float* lsh) {
    const int g = threadIdx.x >> 3; // group 0..31
    const int i = threadIdx.x & 7;  // output row
#pragma unroll 1
    for (int lvl = 1; lvl <= 3; ++lvl) {
        const int c = 64 >> (lvl - 1);
        const int S = 1 << (lvl - 1);
#pragma unroll 1
        for (int m = g; m < c; m += 32) combine8(lm, lsh, 2 * m * S, 2 * m * S + S, i);
        __syncthreads();
    }
    if (threadIdx.x < 64) {
#pragma unroll 1
        for (int lvl = 4; lvl <= 7; ++lvl) {
            const int c = 64 >> (lvl - 1); // 8,4,2,1
            const int S = 1 << (lvl - 1);
            if (g < c) combine8(lm, lsh, 2 * g * S, 2 * g * S + S, i);
            asm volatile("s_waitcnt lgkmcnt(0)" ::: "memory");
        }
    }
}

// packed emission: e2[4] = exp2(em - max), returns max (state pairs in f2)
__device__ __forceinline__ float emit_e2(const f2 ca2[4], const f2 cb2[4][4],
                                         const f2 cc2[4][4], float4 x, f2 e2[4]) {
    f2 x0 = splat(x.x), x1 = splat(x.y), x2 = splat(x.z), x3 = splat(x.w);
    f2 em2[4];
#pragma unroll
    for (int jj = 0; jj < 4; ++jj) {
        f2 t = ca2[jj];
        t = fma2(fma2(cc2[0][jj], x0, cb2[0][jj]), x0, t);
        t = fma2(fma2(cc2[1][jj], x1, cb2[1][jj]), x1, t);
        t = fma2(fma2(cc2[2][jj], x2, cb2[2][jj]), x2, t);
        t = fma2(fma2(cc2[3][jj], x3, cb2[3][jj]), x3, t);
        em2[jj] = t;
    }
    f2 m2 = max2(max2(em2[0], em2[1]), max2(em2[2], em2[3]));
    float me = fmaxf(m2.x, m2.y);
#pragma unroll
    for (int jj = 0; jj < 4; ++jj) {
        e2[jj].x = exp2_raw(em2[jj].x - me);
        e2[jj].y = exp2_raw(em2[jj].y - me);
    }
    return me;
}

// 64-thread parallel setup (keeps main's consts uniform -> SGPR)
__global__ void hmm_setup(const float* __restrict__ x,
                          const float* __restrict__ ut,
                          const float* __restrict__ up,
                          const float* __restrict__ mn,
                          const float* __restrict__ lsd,
                          float* __restrict__ ws) {
    const int lane = threadIdx.x;
    const float L2PI = 1.83787706640934548356f;
    const float LOG2E = 1.44269504088896340736f;

    float v = ut[lane];
    float m = v;
    m = fmaxf(m, __shfl_xor(m, 1));
    m = fmaxf(m, __shfl_xor(m, 2));
    m = fmaxf(m, __shfl_xor(m, 4));
    float e = expf(v - m);
    float s = e;
    s += __shfl_xor(s, 1); s += __shfl_xor(s, 2); s += __shfl_xor(s, 4);
    ws[lane] = e / s;

    float pv = up[lane & 7];
    float pm = pv;
    pm = fmaxf(pm, __shfl_xor(pm, 1));
    pm = fmaxf(pm, __shfl_xor(pm, 2));
    pm = fmaxf(pm, __shfl_xor(pm, 4));
    float pe = expf(pv - pm);
    float ps = pe;
    ps += __shfl_xor(ps, 1); ps += __shfl_xor(ps, 2); ps += __shfl_xor(ps, 4);
    float pival = pe / ps;

    int k = (lane & 31) >> 2, d = lane & 3;
    float lv = lsd[k * D + d];
    float mu = mn[k * D + d];
    float iv = expf(-2.f * lv);
    float bn = mu * iv;
    float cn = -0.5f * iv;
    float aterm = -0.5f * L2PI - lv - 0.5f * mu * mu * iv;
    float ak = aterm;
    ak += __shfl_xor(ak, 1); ak += __shfl_xor(ak, 2);
    if (lane < 32) {
        ws[72 + lane]  = bn * LOG2E;
        ws[104 + lane] = cn * LOG2E;
        if (d == 0) ws[64 + k] = ak * LOG2E;
    }

    float xd = x[d];
    float part = (cn * xd + bn) * xd + aterm;
    part += __shfl_xor(part, 1); part += __shfl_xor(part, 2);
    float pik = __shfl(pival, k);
    if (lane < 32 && d == 0) ws[136 + k] = pik * expf(part);
}

__global__ __launch_bounds__(TPB) void hmm_main(const float* __restrict__ x,
                                                const float* __restrict__ cst,
                                                float* __restrict__ bp,
                                                float* __restrict__ bs) {
    __shared__ __align__(16) float lm[32 * 76];  // 9.7 KB -> up to 16 blocks/CU
    __shared__ float lsh[32];
    const int t = threadIdx.x;
    const int tid = blockIdx.x * TPB + t;

    float Tr[K][K]; // scalar view (uniform -> SGPR)
#pragma unroll
    for (int i = 0; i < K; ++i)
#pragma unroll
        for (int j = 0; j < K; ++j) Tr[i][j] = cst[i * K + j];
    f2 Tr2[K][4];   // packed column-pair view
#pragma unroll
    for (int i = 0; i < K; ++i)
#pragma unroll
        for (int jj = 0; jj < 4; ++jj) { Tr2[i][jj].x = Tr[i][2 * jj]; Tr2[i][jj].y = Tr[i][2 * jj + 1]; }

    f2 ca2[4], cb2[4][4], cc2[4][4]; // [d][state-pair]
#pragma unroll
    for (int jj = 0; jj < 4; ++jj) {
        ca2[jj].x = cst[64 + 2 * jj]; ca2[jj].y = cst[64 + 2 * jj + 1];
#pragma unroll
        for (int d = 0; d < 4; ++d) {
            cb2[d][jj].x = cst[72 + (2 * jj) * 4 + d];  cb2[d][jj].y = cst[72 + (2 * jj + 1) * 4 + d];
            cc2[d][jj].x = cst[104 + (2 * jj) * 4 + d]; cc2[d][jj].y = cst[104 + (2 * jj + 1) * 4 + d];
        }
    }

    // full-chunk register prefetch: one latency exposure per chunk
    const float4* xv = reinterpret_cast<const float4*>(x) + (size_t)tid * CHUNK;
    float4 xr[CHUNK];
#pragma unroll
    for (int q = 0; q < CHUNK; ++q) xr[q] = xv[q];

    // Chunk transfer = Tr*S0*S1*S2*S3, S=(D_a·Tr·D_b); T packed as f2[8][4]
    f2 T2[K][4];
    float shift;
    {
        f2 eB[4];
        float meB = emit_e2(ca2, cb2, cc2, xr[1], eB);
        if (tid == 0) {
#pragma unroll
            for (int i = 0; i < K; ++i) {
                f2 a0 = splat(cst[136 + i]);
#pragma unroll
                for (int jj = 0; jj < 4; ++jj) T2[i][jj] = a0 * Tr2[i][jj] * eB[jj];
            }
            shift = meB;
        } else {
            f2 eA[4];
            float meA = emit_e2(ca2, cb2, cc2, xr[0], eA);
#pragma unroll
            for (int i = 0; i < K; ++i) {
                f2 ei = splat((i & 1) ? eA[i >> 1].y : eA[i >> 1].x);
#pragma unroll
                for (int jj = 0; jj < 4; ++jj) T2[i][jj] = ei * Tr2[i][jj] * eB[jj];
            }
            shift = meA + meB;
        }
    }

#pragma unroll
    for (int p = 1; p < 4; ++p) {
        f2 eA[4], eB[4];
        float meA = emit_e2(ca2, cb2, cc2, xr[2 * p], eA);
        float meB = emit_e2(ca2, cb2, cc2, xr[2 * p + 1], eB);
        shift += meA + meB;
        // T <- ((T .col eA) * Tr) .col eB, row-wise in place
#pragma unroll
        for (int i = 0; i < K; ++i) {
            f2 r2[4];
#pragma unroll
            for (int kk = 0; kk < 4; ++kk) r2[kk] = T2[i][kk] * eA[kk];
            f2 u[4];
#pragma unroll
            for (int jj = 0; jj < 4; ++jj) u[jj] = splat(r2[0].x) * Tr2[0][jj];
#pragma unroll
            for (int k = 1; k < 8; ++k) {
                f2 rk = splat((k & 1) ? r2[k >> 1].y : r2[k >> 1].x);
#pragma unroll
                for (int jj = 0; jj < 4; ++jj) u[jj] = fma2(rk, Tr2[k][jj], u[jj]);
            }
#pragma unroll
            for (int jj = 0; jj < 4; ++jj) T2[i][jj] = u[jj] * eB[jj];
        }
    }

    if (tid != 0) {
        // T <- Tr * T, column-pair in place
#pragma unroll
        for (int jj = 0; jj < 4; ++jj) {
            f2 c[K];
#pragma unroll
            for (int k = 0; k < K; ++k) c[k] = T2[k][jj];
#pragma unroll
            for (int i = 0; i < K; ++i) {
                f2 a = splat(Tr[i][0]) * c[0];
#pragma unroll
                for (int k = 1; k < K; ++k) a = fma2(splat(Tr[i][k]), c[k], a);
                T2[i][jj] = a;
            }
        }
    }

    renorm2(T2, shift);

    hybrid_tree64(T2, shift, lm, lsh);

    // publish block partial, transposed per-span for coalesced mid reads:
    // float j of matrix m -> bp[s*8192 + (j>>2)*512 + ml*4 + (j&3)], s=m>>7, ml=m&127
    {
        const int s = blockIdx.x >> 7;
        const int ml = blockIdx.x & 127;
        bp[(size_t)s * 8192 + (size_t)(t >> 2) * 512 + ml * 4 + (t & 3)] = lm[t];
        if (t == 0) bs[s * 128 + ml] = lsh[0];
    }
}

// Stage 2: NMID=32 blocks; block s tree-reduces its span's 128 matrices.
// Loads are fully lane-coalesced thanks to the transposed bp layout.
__global__ __launch_bounds__(256) void hmm_mid(const float* __restrict__ bp,
                                               const float* __restrict__ bs,
                                               float* __restrict__ bp2,
                                               float* __restrict__ bs2) {
    __shared__ __align__(16) float lm[128 * 76];
    __shared__ float lsh[128];
    const int t = threadIdx.x;
    const int s = blockIdx.x;
    const float4* bp4 = reinterpret_cast<const float4*>(bp) + (size_t)s * 2048;

    // 8 coalesced 1KB wave-loads; scatter into LDS matrix slots
#pragma unroll
    for (int k = 0; k < 8; ++k) {
        float4 v = bp4[k * 256 + t];
        int q = 2 * k + (t >> 7);     // float4 index 0..15
        int ml = t & 127;             // matrix slot
        matp4(lm, ml)[q] = v;
    }
    if (t < 128) lsh[t] = bs[s * 128 + t];
    __syncthreads();

    tree_levels256(lm, lsh);

    if (t == 0) {
        float4* o4 = reinterpret_cast<float4*>(bp2 + (size_t)s * 64);
        const float4* l4 = reinterpret_cast<const float4*>(lm); // slot 0 contiguous
#pragma unroll
        for (int q = 0; q < 16; ++q) o4[q] = l4[q];
        bs2[s] = lsh[0];
    }
}

// Stage 3: one 128-thread block reduces the NMID=32 partials (5 levels), emits scalar
__global__ __launch_bounds__(128) void hmm_final(const float* __restrict__ bp2,
                                                 const float* __restrict__ bs2,
                                                 float* __restrict__ out) {
    __shared__ __align__(16) float lm[32 * 76];
    __shared__ float lsh[32];
    const int t = threadIdx.x;
    const int g = t >> 3; // group 0..15
    const int i = t & 7;  // row

    // coalesced load of 32*64 floats: thread t moves float4s [4t .. 4t+3]
    {
        const float4* src = reinterpret_cast<const float4*>(bp2);
#pragma unroll
        for (int j = 0; j < 4; ++j) {
            int f = t * 4 + j;
            int mat = f >> 4, off = f & 15;
            matp4(lm, mat)[off] = src[f];
        }
    }
    if (t < 32) lsh[t] = bs2[t];
    __syncthreads();

    combine8(lm, lsh, 2 * g, 2 * g + 1, i);              // 32 -> 16
    __syncthreads();
    if (g < 8) combine8(lm, lsh, 4 * g, 4 * g + 2, i);   // 16 -> 8
    __syncthreads();
    if (g < 4) combine8(lm, lsh, 8 * g, 8 * g + 4, i);   // 8 -> 4
    __syncthreads();
    if (g < 2) combine8(lm, lsh, 16 * g, 16 * g + 8, i); // 4 -> 2
    __syncthreads();
    if (g < 1) combine8(lm, lsh, 0, 16, i);              // 2 -> 1
    __syncthreads();

    if (t == 0) {
        double sdbl = 0.0;
#pragma unroll
        for (int q = 0; q < 64; ++q) sdbl += (double)lm[q];
        out[0] = (float)(log(sdbl) + (double)lsh[0] * 0.69314718055994530942);
    }
}

extern "C" void kernel_launch(void* const* d_in, const int* in_sizes, int n_in,
                              void* d_out, int out_size, void* d_ws, size_t ws_size,
                              hipStream_t stream) {
    (void)in_sizes; (void)n_in; (void)out_size; (void)ws_size;
    const float* x  = (const float*)d_in[0];
    const float* ut = (const float*)d_in[1];
    const float* up = (const float*)d_in[2];
    const float* mn = (const float*)d_in[3];
    const float* ls = (const float*)d_in[4];
    float* ws  = (float*)d_ws;
    float* out = (float*)d_out;
    float* bp  = ws + 256;
    float* bs  = bp + (size_t)NBLK * 64;
    float* bp2 = bs + NBLK;
    float* bs2 = bp2 + (size_t)NMID * 64;

    hmm_setup<<<1, 64, 0, stream>>>(x, ut, up, mn, ls, ws);
    hmm_main<<<NBLK, TPB, 0, stream>>>(x, ws, bp, bs);
    hmm_mid<<<NMID, 256, 0, stream>>>(bp, bs, bp2, bs2);
    hmm_final<<<1, 128, 0, stream>>>(bp2, bs2, out);
}